// Round 2
// baseline (1707.349 us; speedup 1.0000x reference)
//
#include <hip/hip_runtime.h>
#include <hip/hip_bf16.h>
#include <math.h>

// Problem dims (fixed by reference)
#define T_STEPS 512
#define BATCH   64
#define DIN     256
#define HID     1024
#define DOUT    256
#define NBLK    64      // rnn blocks: 4 row-groups x 16 col-groups

typedef __attribute__((ext_vector_type(8))) _Float16 f16x8;
typedef __attribute__((ext_vector_type(4))) float    f32x4;
typedef __attribute__((ext_vector_type(4))) int      i32x4;
typedef unsigned long long ull;

static __device__ __forceinline__ unsigned short f2h_bits(float f) {
    union { _Float16 h; unsigned short u; } v; v.h = (_Float16)f; return v.u;
}
static __device__ __forceinline__ float h2f_bits(unsigned short u) {
    union { unsigned short u; _Float16 h; } v; v.u = u; return (float)v.h;
}

// fast tanh: 1 - 2/(exp(2|x|)+1), native v_exp/v_rcp (~1e-6 abs err, exact sat at +-1)
static __device__ __forceinline__ float fast_tanh(float x) {
    float ax = __builtin_fabsf(x);
    float e  = __expf(2.0f * ax);
    float r  = 1.0f - 2.0f * __builtin_amdgcn_rcpf(e + 1.0f);
    return __builtin_copysignf(r, x);
}

// Coherent (cross-XCD) ops: agent-scope relaxed atomics -> sc0|sc1 (L2-bypass /
// write-through to MALL).
static __device__ __forceinline__ void coh_store8(ull* p, ull v) {
    __hip_atomic_store(p, v, __ATOMIC_RELAXED, __HIP_MEMORY_SCOPE_AGENT);
}

// ---------------- convert Wx -> WxT fp16 hi/lo planes ----------------
__global__ __launch_bounds__(256) void convert_wxt(const float* __restrict__ Wx,
                                                   unsigned short* __restrict__ wxt_hi,
                                                   unsigned short* __restrict__ wxt_lo) {
    int o = blockIdx.x * 256 + threadIdx.x;  // 262144 total
    int d = o & (DIN - 1);
    int j = o >> 8;
    float f = Wx[(size_t)d * HID + j];
    _Float16 hi = (_Float16)f;
    _Float16 lo = (_Float16)(f - (float)hi);
    union { _Float16 h; unsigned short u; } a, b;
    a.h = hi; b.h = lo;
    wxt_hi[(size_t)j * DIN + d] = a.u;
    wxt_lo[(size_t)j * DIN + d] = b.u;
}

// ---------------- pre = x @ Wx + b, in the rnn consumer's unit layout ----------
// 8-B unit for (t, block bx=r*16+c, wave w, lane=(q<<5|p<<4|m)):
//   4 fp16 = pre[t][row 16r+m][cols 64c+16w+8p+4q .. +4)
// 3-term fp16 split: x_hi*W_hi + x_lo*W_hi + x_hi*W_lo (lo*lo ~2^-22, dropped).
__global__ __launch_bounds__(256) void gemm_pre(const float* __restrict__ x,
                                                const unsigned short* __restrict__ wxt_hi,
                                                const unsigned short* __restrict__ wxt_lo,
                                                const float* __restrict__ bias,
                                                ull* __restrict__ pre_r) {
    __shared__ unsigned short ldsP[64 * 68];   // 64 rows x 64 cols fp16, stride 68
    int t = blockIdx.x, y = blockIdx.y;        // rows [64t..), cols [64y..)
    int wave = threadIdx.x >> 6, lane = threadIdx.x & 63;
    int l15 = lane & 15, lkq = lane >> 4;
    int nb = y * 64;

    f32x4 acc[4] = {};
    const float* aptr = x + (size_t)(t * 64 + wave * 16 + l15) * DIN + lkq * 8;
#pragma unroll
    for (int ks = 0; ks < 8; ++ks) {
        float4 f0 = *(const float4*)(aptr + ks * 32);
        float4 f1 = *(const float4*)(aptr + ks * 32 + 4);
        float ff[8] = { f0.x, f0.y, f0.z, f0.w, f1.x, f1.y, f1.z, f1.w };
        union { _Float16 f[8]; f16x8 h; } uhi, ulo;
#pragma unroll
        for (int j = 0; j < 8; ++j) {
            _Float16 hi = (_Float16)ff[j];
            uhi.f[j] = hi;
            ulo.f[j] = (_Float16)(ff[j] - (float)hi);
        }
#pragma unroll
        for (int nt = 0; nt < 4; ++nt) {
            size_t boff = (size_t)(nb + nt * 16 + l15) * DIN + ks * 32 + lkq * 8;
            f16x8 bhi = *(const f16x8*)(wxt_hi + boff);
            f16x8 blo = *(const f16x8*)(wxt_lo + boff);
            acc[nt] = __builtin_amdgcn_mfma_f32_16x16x32_f16(uhi.h, bhi, acc[nt], 0, 0, 0);
            acc[nt] = __builtin_amdgcn_mfma_f32_16x16x32_f16(ulo.h, bhi, acc[nt], 0, 0, 0);
            acc[nt] = __builtin_amdgcn_mfma_f32_16x16x32_f16(uhi.h, blo, acc[nt], 0, 0, 0);
        }
    }
#pragma unroll
    for (int nt = 0; nt < 4; ++nt) {
        float bb = bias[nb + nt * 16 + l15];
#pragma unroll
        for (int reg = 0; reg < 4; ++reg)
            ldsP[(16 * wave + lkq * 4 + reg) * 68 + nt * 16 + l15] = f2h_bits(acc[nt][reg] + bb);
    }
    __syncthreads();
#pragma unroll
    for (int i = 0; i < 4; ++i) {
        int u = threadIdx.x + 256 * i;            // 1024 units
        int rr = u >> 8, w2 = (u >> 6) & 3, ln = u & 63;
        int mm = ln & 15, pp = (ln >> 4) & 1, qq = ln >> 5;
        int row = rr * 16 + mm, coloff = 16 * w2 + 8 * pp + 4 * qq;
        ull v = *(const ull*)&ldsP[row * 68 + coloff];
        pre_r[((size_t)(t * 64 + rr * 16 + y) * 4 + w2) * 64 + ln] = v;
    }
}

// ---------------- persistent recurrence kernel ----------------
// 64 blocks x 256 threads. Block bx: c=bx&15 (cols [64c..64c+64)), r=bx>>4
// (rows [16r..16r+16)). Wave w owns K range [256w..256w+256); its Wh slice
// (32 KB fp16) lives in REGISTERS.
//
// TAGGED h layout (R1): logical 16B unit u = r*2048 + ks*64 + lkq*16 + m
// (h[16r+m][ks*32+lkq*8 .. +8)) becomes 32 bytes:
//   {h0,h1,tag32}{h2,h3,tag32}{h4,h5,tag32}{h6,h7,tag32}   (4 x 8B atomic units)
// tag = index of the h it carries (h_t -> tag t). Producer stores data+tag in
// ONE 8B atomic store -> no release fence, no flag array, no separate flag
// poll: the consumer's data load IS the readiness check (tag==t in the same
// 16B load as the data). Tags are monotone per slot (t-3 -> t, no ABA);
// triple-buffer overwrite safety by the same 2-level flag ancestry as before
// (a t+3 writer transitively observed tag stores that are data-dependent on
// ALL 64 waves' h_t loads). Buffers memset to 0xFF -> initial tag = -1.
__global__ __launch_bounds__(256, 1) void rnn_persistent(const float* __restrict__ Wh,
                                                         const ull* __restrict__ pre_r,
                                                         unsigned short* __restrict__ hbuf) {
    __shared__ float ldsR[2][4][16 * 68];   // [parity][wave][row*68+col] = 34816 B
    const int bx = blockIdx.x;
    const int c = bx & 15, r = bx >> 4;
    const int tid = threadIdx.x;
    const int w = tid >> 6, lane = tid & 63;
    const int l15 = lane & 15, lkq = lane >> 4;
    const int p = (lane >> 4) & 1, q = lane >> 5;
    const int m = l15;

    // One-time: B-fragments (Wh[k][col], k in wave range, cols 64c..64c+64) -> regs.
    f16x8 bfr[8][4];
#pragma unroll
    for (int ksl = 0; ksl < 8; ++ksl)
#pragma unroll
        for (int nt = 0; nt < 4; ++nt) {
            union { _Float16 f[8]; f16x8 h; } u;
            int k0 = w * 256 + ksl * 32 + lkq * 8;
            int col = c * 64 + nt * 16 + l15;
#pragma unroll
            for (int j = 0; j < 8; ++j)
                u.f[j] = (_Float16)Wh[(size_t)(k0 + j) * HID + col];
            bfr[ksl][nt] = u.h;
        }

    const int BUFB = 262144;              // 256 KB per tagged buffer
    char* hb = (char*)hbuf;               // 3 buffers x 256 KB
    const char* hc = hb + BUFB;           // read  at t=1 (h_1)
    char*       hn = hb + 2 * BUFB;       // write at t=1 (h_2)
    char*       hx = hb;                  // write at t=2

    // This thread's h-store unit: old 8B index (2*unit16 + q); tagged base = x2 ulls
    const size_t st_unit8 =
        2 * ((size_t)r * 2048 + (size_t)(2 * c + (w >> 1)) * 64 + (2 * (w & 1) + p) * 16 + m) + q;

    const ull* myPre = pre_r + ((size_t)bx * 4 + w) * 64 + lane;
#define PRE_AT(t) myPre[(size_t)(t) * 16384]

    // t = 0: h1 = tanh(pre0) (h0 == 0) -> buf1, tag 1.
    {
        union { _Float16 f[4]; ull u; } pv; pv.u = PRE_AT(0);
        union { _Float16 f[4]; ull u; } hv;
        hv.f[0] = (_Float16)fast_tanh((float)pv.f[0]);
        hv.f[1] = (_Float16)fast_tanh((float)pv.f[1]);
        hv.f[2] = (_Float16)fast_tanh((float)pv.f[2]);
        hv.f[3] = (_Float16)fast_tanh((float)pv.f[3]);
        unsigned lo = (unsigned)(hv.u & 0xffffffffull), hi = (unsigned)(hv.u >> 32);
        ull* bp = (ull*)(hb + BUFB) + 2 * st_unit8;
        coh_store8(bp,     ((ull)1u << 32) | lo);
        coh_store8(bp + 1, ((ull)1u << 32) | hi);
    }

    ull pv_next = PRE_AT(1);

    for (int t = 1; t <= 510; ++t) {
        union { _Float16 f[4]; ull u; } pvc; pvc.u = pv_next;
        if (t < 510) pv_next = PRE_AT(t + 1);

        // A import + readiness in one: 16 x 16B L2-bypassing loads (one vmcnt
        // window); each 16B = {d,tag,d,tag}. Retry until every tag == t.
        i32x4 a2[16];
        const char* abase = hc + ((size_t)r * 2048 + (size_t)(8 * w) * 64 + lane) * 32;
        for (;;) {
#pragma unroll
            for (int i = 0; i < 8; ++i) {
                asm volatile("global_load_dwordx4 %0, %1, off sc0 sc1"
                             : "=v"(a2[2 * i])
                             : "v"((const void*)(abase + (size_t)i * 2048)));
                asm volatile("global_load_dwordx4 %0, %1, off offset:16 sc0 sc1"
                             : "=v"(a2[2 * i + 1])
                             : "v"((const void*)(abase + (size_t)i * 2048)));
            }
            asm volatile("s_waitcnt vmcnt(0)" ::: "memory");
            int ok = 1;
#pragma unroll
            for (int i = 0; i < 16; ++i)
                ok &= (a2[i].y == t) & (a2[i].w == t);
            if (__ballot(ok != 0) == ~0ull) break;
            __builtin_amdgcn_s_sleep(1);
        }
        __builtin_amdgcn_sched_barrier(0);

        f32x4 acc0 = {}, acc1 = {}, acc2 = {}, acc3 = {};
#pragma unroll
        for (int ksl = 0; ksl < 8; ++ksl) {
            i32x4 av4 = { a2[2 * ksl].x, a2[2 * ksl].z, a2[2 * ksl + 1].x, a2[2 * ksl + 1].z };
            union { i32x4 i; f16x8 h; } av; av.i = av4;
            acc0 = __builtin_amdgcn_mfma_f32_16x16x32_f16(av.h, bfr[ksl][0], acc0, 0, 0, 0);
            acc1 = __builtin_amdgcn_mfma_f32_16x16x32_f16(av.h, bfr[ksl][1], acc1, 0, 0, 0);
            acc2 = __builtin_amdgcn_mfma_f32_16x16x32_f16(av.h, bfr[ksl][2], acc2, 0, 0, 0);
            acc3 = __builtin_amdgcn_mfma_f32_16x16x32_f16(av.h, bfr[ksl][3], acc3, 0, 0, 0);
        }

        // Partial sums -> parity LDS (row = lkq*4+reg, col = nt*16+l15).
        float* R = &ldsR[t & 1][w][0];
#pragma unroll
        for (int reg = 0; reg < 4; ++reg) {
            R[(lkq * 4 + reg) * 68 + l15]      = acc0[reg];
            R[(lkq * 4 + reg) * 68 + 16 + l15] = acc1[reg];
            R[(lkq * 4 + reg) * 68 + 32 + l15] = acc2[reg];
            R[(lkq * 4 + reg) * 68 + 48 + l15] = acc3[reg];
        }
        __syncthreads();   // the ONE barrier per step

        // Reduce across 4 waves, add pre, tanh, pack, tagged coherent stores.
        const int coloff = 16 * w + 8 * p + 4 * q;
        f32x4 s;
        s  = *(const f32x4*)&ldsR[t & 1][0][m * 68 + coloff];
        s += *(const f32x4*)&ldsR[t & 1][1][m * 68 + coloff];
        s += *(const f32x4*)&ldsR[t & 1][2][m * 68 + coloff];
        s += *(const f32x4*)&ldsR[t & 1][3][m * 68 + coloff];
        union { _Float16 f[4]; ull u; } hv;
        hv.f[0] = (_Float16)fast_tanh(s[0] + (float)pvc.f[0]);
        hv.f[1] = (_Float16)fast_tanh(s[1] + (float)pvc.f[1]);
        hv.f[2] = (_Float16)fast_tanh(s[2] + (float)pvc.f[2]);
        hv.f[3] = (_Float16)fast_tanh(s[3] + (float)pvc.f[3]);
        {
            unsigned tag = (unsigned)(t + 1);
            unsigned lo = (unsigned)(hv.u & 0xffffffffull), hi = (unsigned)(hv.u >> 32);
            ull* bp = (ull*)hn + 2 * st_unit8;
            coh_store8(bp,     ((ull)tag << 32) | lo);
            coh_store8(bp + 1, ((ull)tag << 32) | hi);
        }

        // rotate triple buffer
        const char* tmp = hc; hc = hn; hn = hx; hx = (char*)tmp;
    }
#undef PRE_AT
    // h_511 (== H[-2]) is in buf1; kernel end = implicit device release.
}

// ---------------- y = h_final @ W2 + b2 (h in tagged chunk layout) --------
__global__ __launch_bounds__(256) void out_gemm(const unsigned short* __restrict__ hfin,
                                                const float* __restrict__ W2,
                                                const float* __restrict__ b2,
                                                float* __restrict__ out) {
    int b = blockIdx.x;        // batch row, 64
    int j = threadIdx.x;       // out col, 256
    int r = b >> 4, m = b & 15;
    float acc = b2[j];
    for (int ks = 0; ks < 32; ++ks) {
#pragma unroll
        for (int lkq = 0; lkq < 4; ++lkq) {
            const unsigned short* ch =
                hfin + ((size_t)(r * 2048 + ks * 64 + lkq * 16 + m)) * 16;  // 32B tagged units
            int k0 = ks * 32 + lkq * 8;
#pragma unroll
            for (int jj = 0; jj < 8; ++jj)
                acc = fmaf(h2f_bits(ch[(jj >> 1) * 4 + (jj & 1)]),
                           W2[(size_t)(k0 + jj) * DOUT + j], acc);
        }
    }
    out[(size_t)b * DOUT + j] = acc;
}

extern "C" void kernel_launch(void* const* d_in, const int* in_sizes, int n_in,
                              void* d_out, int out_size, void* d_ws, size_t ws_size,
                              hipStream_t stream) {
    const float* x  = (const float*)d_in[0];
    const float* Wx = (const float*)d_in[1];
    const float* Wh = (const float*)d_in[2];
    const float* b  = (const float*)d_in[3];
    const float* W2 = (const float*)d_in[4];
    const float* b2 = (const float*)d_in[5];
    float* out = (float*)d_out;

    // workspace carve (~69.3 MB)
    char* ws = (char*)d_ws;
    unsigned short* hbuf   = (unsigned short*)(ws + 4096);                    // 3 x 256 KB tagged
    unsigned short* wxt_hi = (unsigned short*)(ws + 4096 + 786432);           // 0.5 MB
    unsigned short* wxt_lo = (unsigned short*)(ws + 4096 + 786432 + 524288);  // 0.5 MB
    ull*            pre_r  = (ull*)(ws + 4096 + 786432 + 2 * 524288);         // 64 MB

    (void)hipMemsetAsync(hbuf, 0xFF, 786432, stream);   // tags := -1
    convert_wxt<<<1024, 256, 0, stream>>>(Wx, wxt_hi, wxt_lo);
    gemm_pre<<<dim3(512, 16), 256, 0, stream>>>(x, wxt_hi, wxt_lo, b, pre_r);
    rnn_persistent<<<NBLK, 256, 0, stream>>>(Wh, pre_r, hbuf);
    out_gemm<<<64, 256, 0, stream>>>(hbuf + 131072, W2, b2, out);
}

// Round 7
// 1420.194 us; speedup vs baseline: 1.2022x; 1.2022x over previous
//
#include <hip/hip_runtime.h>
#include <hip/hip_bf16.h>
#include <math.h>

// Problem dims (fixed by reference)
#define T_STEPS 512
#define BATCH   64
#define DIN     256
#define HID     1024
#define DOUT    256
#define NBLK    64      // rnn blocks: 4 row-groups x 16 col-groups

typedef __attribute__((ext_vector_type(8))) _Float16 f16x8;
typedef __attribute__((ext_vector_type(4))) float    f32x4;
typedef __attribute__((ext_vector_type(4))) int      i32x4;
typedef unsigned long long ull;

static __device__ __forceinline__ unsigned short f2h_bits(float f) {
    union { _Float16 h; unsigned short u; } v; v.h = (_Float16)f; return v.u;
}
static __device__ __forceinline__ float h2f_bits(unsigned short u) {
    union { unsigned short u; _Float16 h; } v; v.u = u; return (float)v.h;
}

// fast tanh: 1 - 2/(exp(2|x|)+1), native v_exp/v_rcp (~1e-6 abs err, exact sat at +-1)
static __device__ __forceinline__ float fast_tanh(float x) {
    float ax = __builtin_fabsf(x);
    float e  = __expf(2.0f * ax);
    float r  = 1.0f - 2.0f * __builtin_amdgcn_rcpf(e + 1.0f);
    return __builtin_copysignf(r, x);
}

// Coherent (cross-XCD) ops: agent-scope relaxed atomics -> sc0|sc1 (L2-bypass /
// write-through to MALL). Protocol correctness proven R1 (passed, 1565us).
static __device__ __forceinline__ void coh_store8(ull* p, ull v) {
    __hip_atomic_store(p, v, __ATOMIC_RELAXED, __HIP_MEMORY_SCOPE_AGENT);
}
static __device__ __forceinline__ unsigned coh_load4(const unsigned* p) {
    return __hip_atomic_load(p, __ATOMIC_RELAXED, __HIP_MEMORY_SCOPE_AGENT);
}
static __device__ __forceinline__ void coh_store4(unsigned* p, unsigned v) {
    __hip_atomic_store(p, v, __ATOMIC_RELAXED, __HIP_MEMORY_SCOPE_AGENT);
}

// ---------------- convert Wx -> WxT fp16 hi/lo planes ----------------
// hi = fp16(w), lo = fp16(w - hi): split GEMM cancels W-rounding error.
__global__ __launch_bounds__(256) void convert_wxt(const float* __restrict__ Wx,
                                                   unsigned short* __restrict__ wxt_hi,
                                                   unsigned short* __restrict__ wxt_lo) {
    int o = blockIdx.x * 256 + threadIdx.x;  // 262144 total
    int d = o & (DIN - 1);
    int j = o >> 8;
    float f = Wx[(size_t)d * HID + j];
    _Float16 hi = (_Float16)f;
    _Float16 lo = (_Float16)(f - (float)hi);
    union { _Float16 h; unsigned short u; } a, b;
    a.h = hi; b.h = lo;
    wxt_hi[(size_t)j * DIN + d] = a.u;
    wxt_lo[(size_t)j * DIN + d] = b.u;
}

// ---------------- pre = x @ Wx + b, in the rnn consumer's unit layout ----------
// 8-B unit for (t, block bx=r*16+c, wave w, lane=(q<<5|p<<4|m)):
//   4 fp16 = pre[t][row 16r+m][cols 64c+16w+8p+4q .. +4)
// 2-term fp16 split: x_hi*W_hi + x_hi*W_lo (x_lo term ~2.8e-4 sigma, dropped).
__global__ __launch_bounds__(256) void gemm_pre(const float* __restrict__ x,
                                                const unsigned short* __restrict__ wxt_hi,
                                                const unsigned short* __restrict__ wxt_lo,
                                                const float* __restrict__ bias,
                                                ull* __restrict__ pre_r) {
    __shared__ unsigned short ldsP[64 * 68];   // 64 rows x 64 cols fp16, stride 68
    int t = blockIdx.x, y = blockIdx.y;        // rows [64t..), cols [64y..)
    int wave = threadIdx.x >> 6, lane = threadIdx.x & 63;
    int l15 = lane & 15, lkq = lane >> 4;
    int nb = y * 64;

    f32x4 acc[4] = {};
    const float* aptr = x + (size_t)(t * 64 + wave * 16 + l15) * DIN + lkq * 8;
#pragma unroll
    for (int ks = 0; ks < 8; ++ks) {
        float4 f0 = *(const float4*)(aptr + ks * 32);
        float4 f1 = *(const float4*)(aptr + ks * 32 + 4);
        union { _Float16 f[8]; f16x8 h; } uhi;
        uhi.f[0] = (_Float16)f0.x; uhi.f[1] = (_Float16)f0.y;
        uhi.f[2] = (_Float16)f0.z; uhi.f[3] = (_Float16)f0.w;
        uhi.f[4] = (_Float16)f1.x; uhi.f[5] = (_Float16)f1.y;
        uhi.f[6] = (_Float16)f1.z; uhi.f[7] = (_Float16)f1.w;
#pragma unroll
        for (int nt = 0; nt < 4; ++nt) {
            size_t boff = (size_t)(nb + nt * 16 + l15) * DIN + ks * 32 + lkq * 8;
            f16x8 bhi = *(const f16x8*)(wxt_hi + boff);
            f16x8 blo = *(const f16x8*)(wxt_lo + boff);
            acc[nt] = __builtin_amdgcn_mfma_f32_16x16x32_f16(uhi.h, bhi, acc[nt], 0, 0, 0);
            acc[nt] = __builtin_amdgcn_mfma_f32_16x16x32_f16(uhi.h, blo, acc[nt], 0, 0, 0);
        }
    }
#pragma unroll
    for (int nt = 0; nt < 4; ++nt) {
        float bb = bias[nb + nt * 16 + l15];
#pragma unroll
        for (int reg = 0; reg < 4; ++reg)
            ldsP[(16 * wave + lkq * 4 + reg) * 68 + nt * 16 + l15] = f2h_bits(acc[nt][reg] + bb);
    }
    __syncthreads();
#pragma unroll
    for (int i = 0; i < 4; ++i) {
        int u = threadIdx.x + 256 * i;            // 1024 units
        int rr = u >> 8, w2 = (u >> 6) & 3, ln = u & 63;
        int mm = ln & 15, pp = (ln >> 4) & 1, qq = ln >> 5;
        int row = rr * 16 + mm, coloff = 16 * w2 + 8 * pp + 4 * qq;
        ull v = *(const ull*)&ldsP[row * 68 + coloff];
        pre_r[((size_t)(t * 64 + rr * 16 + y) * 4 + w2) * 64 + ln] = v;
    }
}

// ---------------- persistent recurrence kernel ----------------
// 64 blocks x 256 threads. Block bx: c=bx&15 (cols [64c..64c+64)), r=bx>>4
// (rows [16r..16r+16)). Wave w owns K range [256w..256w+256); its Wh slice
// (32 KB fp16) lives in REGISTERS. h chunks (16B) in A-frag layout per row-group:
//   unit16 = r*2048 + ks*64 + lkq*16 + m  <->  h[16r+m][ks*32+lkq*8 .. +8)
// Per wave per step: early-start poll (16 wave-flags of its 4 producer blocks)
// -> 8 asm sc1 dwordx4 loads (one vmcnt window) -> 32 MFMA -> f32 partials to
// parity-LDS -> 1 barrier -> 4-wave reduce + pre + tanh -> coherent 8B store
// -> per-wave vmcnt drain -> wave flag -> NEXT-t pre prefetch (after the fence
// so the drain never waits on it). h triple-buffered (early-start safety:
// a t+2 writer transitively waited on ALL waves' t-flags via 2-level ancestry).
__global__ __launch_bounds__(256, 1) void rnn_persistent(const float* __restrict__ Wh,
                                                         const ull* __restrict__ pre_r,
                                                         unsigned short* __restrict__ hbuf,
                                                         unsigned* __restrict__ flags) {
    __shared__ float ldsR[2][4][16 * 68];   // [parity][wave][row*68+col] = 34816 B
    const int bx = blockIdx.x;
    const int c = bx & 15, r = bx >> 4;
    const int tid = threadIdx.x;
    const int w = tid >> 6, lane = tid & 63;
    const int l15 = lane & 15, lkq = lane >> 4;
    const int p = (lane >> 4) & 1, q = lane >> 5;
    const int m = l15;

    // One-time: B-fragments (Wh[k][col], k in wave range, cols 64c..64c+64) -> regs.
    f16x8 bfr[8][4];
#pragma unroll
    for (int ksl = 0; ksl < 8; ++ksl)
#pragma unroll
        for (int nt = 0; nt < 4; ++nt) {
            union { _Float16 f[8]; f16x8 h; } u;
            int k0 = w * 256 + ksl * 32 + lkq * 8;
            int col = c * 64 + nt * 16 + l15;
#pragma unroll
            for (int j = 0; j < 8; ++j)
                u.f[j] = (_Float16)Wh[(size_t)(k0 + j) * HID + col];
            bfr[ksl][nt] = u.h;
        }

    char* hb = (char*)hbuf;               // 3 buffers x 128 KB
    const char* hc = hb + 131072;         // read  at t=1 (h_1)
    char*       hn = hb + 2 * 131072;     // write at t=1 (h_2)
    char*       hx = hb;                  // write at t=2

    // This thread's h-store unit (8B): chunk (ks=2c+(w>>1), lkq=2(w&1)+p, m), half q
    const size_t st_unit8 =
        2 * ((size_t)r * 2048 + (size_t)(2 * c + (w >> 1)) * 64 + (2 * (w & 1) + p) * 16 + m) + q;

    const ull* myPre = pre_r + ((size_t)bx * 4 + w) * 64 + lane;
#define PRE_AT(t) myPre[(size_t)(t) * 16384]

    const int myFlag = (bx << 2) + w;
    const int pollIdx = r * 64 + 16 * w + l15;   // 16 wave-flags of 4 producer blocks

    // t = 0: h1 = tanh(pre0) (h0 == 0) -> buf1.
    {
        union { _Float16 f[4]; ull u; } pv; pv.u = PRE_AT(0);
        union { _Float16 f[4]; ull u; } hv;
        hv.f[0] = (_Float16)fast_tanh((float)pv.f[0]);
        hv.f[1] = (_Float16)fast_tanh((float)pv.f[1]);
        hv.f[2] = (_Float16)fast_tanh((float)pv.f[2]);
        hv.f[3] = (_Float16)fast_tanh((float)pv.f[3]);
        coh_store8((ull*)(hb + 131072) + st_unit8, hv.u);
        __builtin_amdgcn_fence(__ATOMIC_RELEASE, "workgroup");   // per-wave vmcnt drain
        if (lane == 0) coh_store4(&flags[myFlag], 1u);
    }

    ull pv_next = PRE_AT(1);

    for (int t = 1; t <= 510; ++t) {
        union { _Float16 f[4]; ull u; } pvc; pvc.u = pv_next;

        // Early-start poll: wave w waits only for its k-range producers.
        {
            const unsigned tt = (unsigned)t;
            for (;;) {
                unsigned v = coh_load4(&flags[pollIdx]);
                if (__ballot(v >= tt) == ~0ull) break;
            }
        }

        // A import: 8 x 16B L2-bypassing loads, ALL in flight, one vmcnt window.
        i32x4 a[8];
        const char* abase = hc + ((size_t)r * 2048 + (size_t)(8 * w) * 64 + lane) * 16;
#pragma unroll
        for (int ksl = 0; ksl < 8; ++ksl)
            asm volatile("global_load_dwordx4 %0, %1, off sc0 sc1"
                         : "=v"(a[ksl])
                         : "v"((const void*)(abase + (size_t)ksl * 1024)));
        asm volatile("s_waitcnt vmcnt(0)" ::: "memory");
        __builtin_amdgcn_sched_barrier(0);

        f32x4 acc0 = {}, acc1 = {}, acc2 = {}, acc3 = {};
#pragma unroll
        for (int ksl = 0; ksl < 8; ++ksl) {
            union { i32x4 i; f16x8 h; } av; av.i = a[ksl];
            acc0 = __builtin_amdgcn_mfma_f32_16x16x32_f16(av.h, bfr[ksl][0], acc0, 0, 0, 0);
            acc1 = __builtin_amdgcn_mfma_f32_16x16x32_f16(av.h, bfr[ksl][1], acc1, 0, 0, 0);
            acc2 = __builtin_amdgcn_mfma_f32_16x16x32_f16(av.h, bfr[ksl][2], acc2, 0, 0, 0);
            acc3 = __builtin_amdgcn_mfma_f32_16x16x32_f16(av.h, bfr[ksl][3], acc3, 0, 0, 0);
        }

        // Partial sums -> parity LDS (row = lkq*4+reg, col = nt*16+l15).
        float* R = &ldsR[t & 1][w][0];
#pragma unroll
        for (int reg = 0; reg < 4; ++reg) {
            R[(lkq * 4 + reg) * 68 + l15]      = acc0[reg];
            R[(lkq * 4 + reg) * 68 + 16 + l15] = acc1[reg];
            R[(lkq * 4 + reg) * 68 + 32 + l15] = acc2[reg];
            R[(lkq * 4 + reg) * 68 + 48 + l15] = acc3[reg];
        }
        __syncthreads();   // the ONE barrier per step

        // Reduce across 4 waves, add pre, tanh, pack, coherent 8B store.
        const int coloff = 16 * w + 8 * p + 4 * q;
        f32x4 s;
        s  = *(const f32x4*)&ldsR[t & 1][0][m * 68 + coloff];
        s += *(const f32x4*)&ldsR[t & 1][1][m * 68 + coloff];
        s += *(const f32x4*)&ldsR[t & 1][2][m * 68 + coloff];
        s += *(const f32x4*)&ldsR[t & 1][3][m * 68 + coloff];
        union { _Float16 f[4]; ull u; } hv;
        hv.f[0] = (_Float16)fast_tanh(s[0] + (float)pvc.f[0]);
        hv.f[1] = (_Float16)fast_tanh(s[1] + (float)pvc.f[1]);
        hv.f[2] = (_Float16)fast_tanh(s[2] + (float)pvc.f[2]);
        hv.f[3] = (_Float16)fast_tanh(s[3] + (float)pvc.f[3]);
        coh_store8((ull*)hn + st_unit8, hv.u);

        __builtin_amdgcn_fence(__ATOMIC_RELEASE, "workgroup");   // per-wave vmcnt drain
        if (t < 510 && lane == 0) coh_store4(&flags[myFlag], (unsigned)(t + 1));

        // Prefetch next pre AFTER the fence so the drain never waits on it.
        if (t < 510) pv_next = PRE_AT(t + 1);

        // rotate triple buffer
        const char* tmp = hc; hc = hn; hn = hx; hx = (char*)tmp;
    }
#undef PRE_AT
    // h_511 (== H[-2]) is in buf1; kernel end = implicit device release.
}

// ---------------- y = h_final @ W2 + b2 (h in group/A-frag chunk layout) --------
__global__ __launch_bounds__(256) void out_gemm(const unsigned short* __restrict__ hfin,
                                                const float* __restrict__ W2,
                                                const float* __restrict__ b2,
                                                float* __restrict__ out) {
    int b = blockIdx.x;        // batch row, 64
    int j = threadIdx.x;       // out col, 256
    int r = b >> 4, m = b & 15;
    float a[8] = {0.f, 0.f, 0.f, 0.f, 0.f, 0.f, 0.f, 0.f};
    for (int ks = 0; ks < 32; ++ks) {
#pragma unroll
        for (int lkq = 0; lkq < 4; ++lkq) {
            const unsigned short* ch =
                hfin + ((size_t)(r * 2048 + ks * 64 + lkq * 16 + m)) * 8;
            int k0 = ks * 32 + lkq * 8;
#pragma unroll
            for (int jj = 0; jj < 8; ++jj)
                a[jj] = fmaf(h2f_bits(ch[jj]), W2[(size_t)(k0 + jj) * DOUT + j], a[jj]);
        }
    }
    float acc = b2[j] + ((a[0] + a[1]) + (a[2] + a[3])) + ((a[4] + a[5]) + (a[6] + a[7]));
    out[(size_t)b * DOUT + j] = acc;
}

extern "C" void kernel_launch(void* const* d_in, const int* in_sizes, int n_in,
                              void* d_out, int out_size, void* d_ws, size_t ws_size,
                              hipStream_t stream) {
    const float* x  = (const float*)d_in[0];
    const float* Wx = (const float*)d_in[1];
    const float* Wh = (const float*)d_in[2];
    const float* b  = (const float*)d_in[3];
    const float* W2 = (const float*)d_in[4];
    const float* b2 = (const float*)d_in[5];
    float* out = (float*)d_out;

    // workspace carve (~69 MB)
    char* ws = (char*)d_ws;
    unsigned*       flags  = (unsigned*)ws;                                   // 1 KB (256 wave-flags)
    unsigned short* hbuf   = (unsigned short*)(ws + 4096);                    // 3 x 128 KB
    unsigned short* wxt_hi = (unsigned short*)(ws + 4096 + 393216);           // 0.5 MB
    unsigned short* wxt_lo = (unsigned short*)(ws + 4096 + 393216 + 524288);  // 0.5 MB
    ull*            pre_r  = (ull*)(ws + 4096 + 393216 + 2 * 524288);         // 64 MB

    (void)hipMemsetAsync(flags, 0, 4096, stream);
    convert_wxt<<<1024, 256, 0, stream>>>(Wx, wxt_hi, wxt_lo);
    gemm_pre<<<dim3(512, 16), 256, 0, stream>>>(x, wxt_hi, wxt_lo, b, pre_r);
    rnn_persistent<<<NBLK, 256, 0, stream>>>(Wh, pre_r, hbuf, flags);
    out_gemm<<<64, 256, 0, stream>>>(hbuf + 65536, W2, b2, out);
}